// Round 4
// baseline (333.099 us; speedup 1.0000x reference)
//
#include <hip/hip_runtime.h>
#include <stdint.h>

// CovPool: B=32, N=16384, D=64 fp32 -> per-batch cov (64x64), triu, globally
// sorted 66560 fp32 outputs.
// R4: kill the LDS transpose round-trip in the cov K-loop. MFMA A/B frags
// (m=lane&15, k=quad*8+j) are loaded DIRECTLY from global with immediate
// offsets (32 dword loads/iter), cvt+packed in registers. No LDS, no lgkmcnt
// chain -> loads pipeline across iterations. Mean via quad shuffle-reduce.
//
// Partial-path ws layout (zero region first = 262208 B):
//   hist      [65536 u32]       @ 0
//   counts    [16 u32]          @ 262144   <- zero region ends 262208
//   offsets   [65536 u32]       @ 262208
//   blocksums [256 u32]         @ 524352
//   tri       [66560 f32]       @ 525376
//   wl_small  [33280 uint2]     @ 791616
//   wl_large  [1024 uint2]      @ 1057856
//   partials  [1024][2624] f32  @ 1066048  (ends 11813952)

#define BATCHES 32
#define NSAMP   16384
#define DIM     64
#define LAMBDA  0.01f
#define NTRI    2080
#define NOUT    (BATCHES * NTRI)   // 66560

#define CHUNKS_PER_BATCH 32
#define SAMP_PER_BLOCK   (NSAMP / CHUNKS_PER_BATCH)  // 512
#define SAMP_PER_WAVE    (SAMP_PER_BLOCK / 4)        // 128
#define PARTIAL_STRIDE   2624                        // 2560 S + 64 msum

typedef __attribute__((ext_vector_type(4))) float f32x4;
typedef __attribute__((ext_vector_type(8))) short s16x8;

__device__ __forceinline__ uint32_t f32_to_bf16(float f) {
    uint32_t u = __builtin_bit_cast(uint32_t, f);
    return (u + 0x7FFFu + ((u >> 16) & 1u)) >> 16;   // RNE
}

__device__ __forceinline__ uint32_t sort_key(float v) {
    uint32_t u = __builtin_bit_cast(uint32_t, v);
    return u ^ (uint32_t)(((int32_t)u >> 31) | 0x80000000u);
}

__constant__ const int c_tmi[10] = {0, 0, 0, 0, 1, 1, 1, 2, 2, 3};
__constant__ const int c_tni[10] = {0, 1, 2, 3, 1, 2, 3, 2, 3, 3};

// ============ shared device body: direct-load MFMA K-loop + tree reduce ======
struct CovLds {
    float red[2][64][41];     // 20992 B (epilogue tree)
    float msum_red[4][64];    // 1024 B
};

template <typename EpilogueFn>
__device__ __forceinline__ void cov_body(const float* __restrict__ x, CovLds& L,
                                         EpilogueFn epi) {
    const int tid  = threadIdx.x;
    const int wave = tid >> 6;
    const int lane = tid & 63;
    const int b     = blockIdx.x / CHUNKS_PER_BATCH;
    const int chunk = blockIdx.x % CHUNKS_PER_BATCH;
    const int n_start = chunk * SAMP_PER_BLOCK + wave * SAMP_PER_WAVE;

    const int l15  = lane & 15;
    const int quad = lane >> 4;

    // lane (quad,l15) loads x[s0 + quad*8 + j][t*16 + l15], j=0..7, t=0..3
    // -> exactly the A/B fragment layout (m/n = l15, k = quad*8+j), per 16-dim
    //    tile t. Offsets j*DIM + t*16 are compile-time immediates.
    const float* xw = x + ((size_t)b * NSAMP + n_start) * DIM
                        + quad * 8 * DIM + l15;

    f32x4 acc[10];
#pragma unroll
    for (int t = 0; t < 10; ++t) acc[t] = (f32x4){0.f, 0.f, 0.f, 0.f};
    float sum_t[4] = {0.f, 0.f, 0.f, 0.f};

    for (int kc = 0; kc < SAMP_PER_WAVE / 32; ++kc) {
        const float* xs = xw + kc * 32 * DIM;
        float v[8][4];
#pragma unroll
        for (int j = 0; j < 8; ++j)
#pragma unroll
            for (int t = 0; t < 4; ++t)
                v[j][t] = xs[j * DIM + t * 16];   // 32 independent dword loads

#pragma unroll
        for (int j = 0; j < 8; ++j)
#pragma unroll
            for (int t = 0; t < 4; ++t) sum_t[t] += v[j][t];

        s16x8 frag[4];
#pragma unroll
        for (int t = 0; t < 4; ++t) {
            uint32_t pk0 = f32_to_bf16(v[0][t]) | (f32_to_bf16(v[1][t]) << 16);
            uint32_t pk1 = f32_to_bf16(v[2][t]) | (f32_to_bf16(v[3][t]) << 16);
            uint32_t pk2 = f32_to_bf16(v[4][t]) | (f32_to_bf16(v[5][t]) << 16);
            uint32_t pk3 = f32_to_bf16(v[6][t]) | (f32_to_bf16(v[7][t]) << 16);
            frag[t] = __builtin_bit_cast(s16x8, make_uint4(pk0, pk1, pk2, pk3));
        }

        acc[0] = __builtin_amdgcn_mfma_f32_16x16x32_bf16(frag[0], frag[0], acc[0], 0, 0, 0);
        acc[1] = __builtin_amdgcn_mfma_f32_16x16x32_bf16(frag[0], frag[1], acc[1], 0, 0, 0);
        acc[2] = __builtin_amdgcn_mfma_f32_16x16x32_bf16(frag[0], frag[2], acc[2], 0, 0, 0);
        acc[3] = __builtin_amdgcn_mfma_f32_16x16x32_bf16(frag[0], frag[3], acc[3], 0, 0, 0);
        acc[4] = __builtin_amdgcn_mfma_f32_16x16x32_bf16(frag[1], frag[1], acc[4], 0, 0, 0);
        acc[5] = __builtin_amdgcn_mfma_f32_16x16x32_bf16(frag[1], frag[2], acc[5], 0, 0, 0);
        acc[6] = __builtin_amdgcn_mfma_f32_16x16x32_bf16(frag[1], frag[3], acc[6], 0, 0, 0);
        acc[7] = __builtin_amdgcn_mfma_f32_16x16x32_bf16(frag[2], frag[2], acc[7], 0, 0, 0);
        acc[8] = __builtin_amdgcn_mfma_f32_16x16x32_bf16(frag[2], frag[3], acc[8], 0, 0, 0);
        acc[9] = __builtin_amdgcn_mfma_f32_16x16x32_bf16(frag[3], frag[3], acc[9], 0, 0, 0);
    }

    // ---- per-dim mean partials: sum over the 4 quads (lanes l15+16q) ----
#pragma unroll
    for (int t = 0; t < 4; ++t) {
        sum_t[t] += __shfl_xor(sum_t[t], 16, 64);
        sum_t[t] += __shfl_xor(sum_t[t], 32, 64);
    }
    if (lane < 16) {
#pragma unroll
        for (int t = 0; t < 4; ++t) L.msum_red[wave][t * 16 + lane] = sum_t[t];
    }

    // ---- in-block tree reduction of 4 waves into wave0 ----
    __syncthreads();
    if (wave == 1 || wave == 3) {
        int slot = wave >> 1;
#pragma unroll
        for (int t = 0; t < 10; ++t)
#pragma unroll
            for (int r = 0; r < 4; ++r) L.red[slot][lane][t * 4 + r] = acc[t][r];
    }
    __syncthreads();
    if (wave == 0 || wave == 2) {
        int slot = wave >> 1;
#pragma unroll
        for (int t = 0; t < 10; ++t)
#pragma unroll
            for (int r = 0; r < 4; ++r) acc[t][r] += L.red[slot][lane][t * 4 + r];
    }
    __syncthreads();
    if (wave == 2) {
#pragma unroll
        for (int t = 0; t < 10; ++t)
#pragma unroll
            for (int r = 0; r < 4; ++r) L.red[0][lane][t * 4 + r] = acc[t][r];
    }
    __syncthreads();
    if (wave == 0) {
#pragma unroll
        for (int t = 0; t < 10; ++t)
#pragma unroll
            for (int r = 0; r < 4; ++r) acc[t][r] += L.red[0][lane][t * 4 + r];
        float msum_tot = L.msum_red[0][lane] + L.msum_red[1][lane] +
                         L.msum_red[2][lane] + L.msum_red[3][lane];
        epi(b, lane, quad, l15, acc, msum_tot);
    }
}

// ---------------- K1p: partial-store variant (no atomics) --------------------
__global__ __launch_bounds__(256, 4) void cov_kernel_p(const float* __restrict__ x,
                                                       float* __restrict__ partials) {
    __shared__ CovLds L;
    float* Pb = partials + (size_t)blockIdx.x * PARTIAL_STRIDE;
    cov_body(x, L, [&](int b, int lane, int quad, int l15, f32x4* acc, float msum) {
#pragma unroll
        for (int t = 0; t < 10; ++t)
#pragma unroll
            for (int r = 0; r < 4; ++r)
                Pb[t * 256 + r * 64 + lane] = acc[t][r];   // coalesced stores
        Pb[2560 + lane] = msum;
    });
}

// ---------------- K1a: atomic fallback variant -------------------------------
__global__ __launch_bounds__(256, 4) void cov_kernel_a(const float* __restrict__ x,
                                                       float* __restrict__ S,
                                                       float* __restrict__ Msum) {
    __shared__ CovLds L;
    cov_body(x, L, [&](int b, int lane, int quad, int l15, f32x4* acc, float msum) {
        float* Sb = S + b * DIM * DIM;
#pragma unroll
        for (int t = 0; t < 10; ++t) {
            int d0 = c_tmi[t] * 16 + quad * 4;
            int e  = c_tni[t] * 16 + l15;
#pragma unroll
            for (int r = 0; r < 4; ++r)
                atomicAdd(&Sb[(d0 + r) * DIM + e], acc[t][r]);
        }
        atomicAdd(&Msum[b * DIM + lane], msum);
    });
}

// ---------------- K2p: reduce partials + finalize + histogram ----------------
__global__ __launch_bounds__(256) void reduce_kernel(const float* __restrict__ partials,
                                                     float* __restrict__ tri,
                                                     uint32_t* __restrict__ hist) {
    __shared__ float msum[DIM];
    const int b = blockIdx.x, tid = threadIdx.x;
    const float* P0 = partials + (size_t)b * CHUNKS_PER_BATCH * PARTIAL_STRIDE;

    float acc10[10];
#pragma unroll
    for (int k = 0; k < 10; ++k) acc10[k] = 0.f;
    float ms = 0.f;
    for (int c = 0; c < CHUNKS_PER_BATCH; ++c) {
        const float* P = P0 + c * PARTIAL_STRIDE;
#pragma unroll
        for (int k = 0; k < 10; ++k) acc10[k] += P[tid + 256 * k];  // coalesced
        if (tid < DIM) ms += P[2560 + tid];
    }
    if (tid < DIM) msum[tid] = ms;
    __syncthreads();

    const int r = tid >> 6, lane = tid & 63, quad = lane >> 4, l15 = lane & 15;
#pragma unroll
    for (int k = 0; k < 10; ++k) {
        int row = c_tmi[k] * 16 + quad * 4 + r;
        int col = c_tni[k] * 16 + l15;
        if (row <= col) {
            float v = (acc10[k] - msum[row] * msum[col] * (1.0f / NSAMP)) * (1.0f / (NSAMP - 1));
            if (row == col) v += LAMBDA;
            int p = row * 64 - (row * (row + 1)) / 2 + col;
            tri[b * NTRI + p] = v;
            atomicAdd(&hist[sort_key(v) >> 16], 1u);
        }
    }
}

// ---------------- K2a: finalize (atomic fallback path) -----------------------
__global__ void finalize_kernel(const float* __restrict__ S,
                                const float* __restrict__ Msum,
                                float* __restrict__ tri,
                                uint32_t* __restrict__ hist) {
    int t = blockIdx.x * blockDim.x + threadIdx.x;
    int b = t >> 12, de = t & 4095, d = de >> 6, e = de & 63;
    if (d > e) return;
    float ssum = S[b * 4096 + d * 64 + e];
    float md = Msum[b * 64 + d], me = Msum[b * 64 + e];
    float v = (ssum - md * me * (1.0f / NSAMP)) * (1.0f / (NSAMP - 1));
    if (d == e) v += LAMBDA;
    int p = d * 64 - (d * (d + 1)) / 2 + e;
    tri[b * NTRI + p] = v;
    atomicAdd(&hist[sort_key(v) >> 16], 1u);
}

// ---------------- K3a: per-256-bucket partial sums ---------------------------
__global__ __launch_bounds__(256) void scanA_kernel(const uint32_t* __restrict__ hist,
                                                    uint32_t* __restrict__ blocksums) {
    __shared__ uint32_t s[256];
    int tid = threadIdx.x;
    s[tid] = hist[blockIdx.x * 256 + tid];
    __syncthreads();
    for (int off = 128; off > 0; off >>= 1) {
        if (tid < off) s[tid] += s[tid + off];
        __syncthreads();
    }
    if (tid == 0) blocksums[blockIdx.x] = s[0];
}

// ---------------- K3b: offsets + worklists -----------------------------------
__global__ __launch_bounds__(256) void scanB_kernel(const uint32_t* __restrict__ hist,
                                                    const uint32_t* __restrict__ blocksums,
                                                    uint32_t* __restrict__ offsets,
                                                    uint2* __restrict__ wl_small,
                                                    uint2* __restrict__ wl_large,
                                                    uint32_t* __restrict__ counts) {
    __shared__ uint32_t bs[256];
    __shared__ uint32_t sc[256];
    int tid = threadIdx.x, bid = blockIdx.x;

    bs[tid] = blocksums[tid];
    __syncthreads();
    for (int off = 1; off < 256; off <<= 1) {
        uint32_t a = (tid >= off) ? bs[tid - off] : 0u;
        __syncthreads();
        bs[tid] += a;
        __syncthreads();
    }
    uint32_t base = (bid > 0) ? bs[bid - 1] : 0u;

    uint32_t v = hist[bid * 256 + tid];
    sc[tid] = v;
    __syncthreads();
    for (int off = 1; off < 256; off <<= 1) {
        uint32_t a = (tid >= off) ? sc[tid - off] : 0u;
        __syncthreads();
        sc[tid] += a;
        __syncthreads();
    }
    uint32_t excl = base + sc[tid] - v;
    offsets[bid * 256 + tid] = excl;
    if (v >= 2u) {
        if (v <= 64u) {
            uint32_t w = atomicAdd(&counts[0], 1u);
            wl_small[w] = make_uint2(excl, v);
        } else {
            uint32_t w = atomicAdd(&counts[1], 1u);
            wl_large[w] = make_uint2(excl, v);
        }
    }
}

// ---------------- K4: scatter into bucket positions --------------------------
__global__ void scatter_kernel(const float* __restrict__ tri,
                               uint32_t* __restrict__ offsets,
                               float* __restrict__ out) {
    int i = blockIdx.x * blockDim.x + threadIdx.x;
    if (i >= NOUT) return;
    float v = tri[i];
    uint32_t pos = atomicAdd(&offsets[sort_key(v) >> 16], 1u);
    out[pos] = v;
}

// ---------------- K5a: wave-level shuffle bitonic for runs <= 64 -------------
__global__ __launch_bounds__(256) void runsort_small_kernel(float* __restrict__ out,
                                                            const uint2* __restrict__ wl,
                                                            const uint32_t* __restrict__ counts) {
    uint32_t nw = counts[0];
    int wave = threadIdx.x >> 6, lane = threadIdx.x & 63;
    for (uint32_t r = blockIdx.x * 4 + wave; r < nw; r += gridDim.x * 4) {
        uint2 e = wl[r];
        uint32_t start = e.x, cnt = e.y;
        float v = (lane < (int)cnt) ? out[start + lane] : __builtin_inff();
#pragma unroll
        for (uint32_t k = 2; k <= 64; k <<= 1)
            for (uint32_t j = k >> 1; j > 0; j >>= 1) {
                float p = __shfl_xor(v, (int)j, 64);
                bool keepmin = (((lane & k) == 0u) == ((lane & j) == 0u));
                v = keepmin ? fminf(v, p) : fmaxf(v, p);
            }
        if (lane < (int)cnt) out[start + lane] = v;
    }
}

// ---------------- K5b: LDS bitonic for runs 65..8192 -------------------------
#define SORT_CAP 8192
__global__ __launch_bounds__(256) void runsort_large_kernel(float* __restrict__ out,
                                                            const uint2* __restrict__ wl,
                                                            const uint32_t* __restrict__ counts) {
    __shared__ float buf[SORT_CAP];
    uint32_t nw = counts[1];
    for (uint32_t w = blockIdx.x; w < nw; w += gridDim.x) {
        uint2 ent = wl[w];
        uint32_t start = ent.x, cnt = ent.y;
        if (cnt > SORT_CAP) continue;
        uint32_t m = 1;
        while (m < cnt) m <<= 1;
        for (uint32_t i = threadIdx.x; i < m; i += blockDim.x)
            buf[i] = (i < cnt) ? out[start + i] : __builtin_inff();
        __syncthreads();
        for (uint32_t k = 2; k <= m; k <<= 1) {
            for (uint32_t j = k >> 1; j > 0; j >>= 1) {
                for (uint32_t i = threadIdx.x; i < m; i += blockDim.x) {
                    uint32_t ixj = i ^ j;
                    if (ixj > i) {
                        float a = buf[i], c = buf[ixj];
                        bool up = ((i & k) == 0u);
                        if ((a > c) == up) { buf[i] = c; buf[ixj] = a; }
                    }
                }
                __syncthreads();
            }
        }
        for (uint32_t i = threadIdx.x; i < cnt; i += blockDim.x)
            out[start + i] = buf[i];
        __syncthreads();
    }
}

extern "C" void kernel_launch(void* const* d_in, const int* in_sizes, int n_in,
                              void* d_out, int out_size, void* d_ws, size_t ws_size,
                              hipStream_t stream) {
    const float* x = (const float*)d_in[0];
    float* out = (float*)d_out;
    char* ws = (char*)d_ws;

    const size_t NEED_P = 1066048 + (size_t)1024 * PARTIAL_STRIDE * 4;  // 11.8 MB

    if (ws_size >= NEED_P) {
        uint32_t* hist      = (uint32_t*)(ws);
        uint32_t* counts    = (uint32_t*)(ws + 262144);
        uint32_t* offsets   = (uint32_t*)(ws + 262208);
        uint32_t* blocksums = (uint32_t*)(ws + 524352);
        float*    tri       = (float*)(ws + 525376);
        uint2*    wl_small  = (uint2*)(ws + 791616);
        uint2*    wl_large  = (uint2*)(ws + 1057856);
        float*    partials  = (float*)(ws + 1066048);

        hipMemsetAsync(d_ws, 0, 262208, stream);  // hist + counts
        cov_kernel_p<<<BATCHES * CHUNKS_PER_BATCH, 256, 0, stream>>>(x, partials);
        reduce_kernel<<<BATCHES, 256, 0, stream>>>(partials, tri, hist);
        scanA_kernel<<<256, 256, 0, stream>>>(hist, blocksums);
        scanB_kernel<<<256, 256, 0, stream>>>(hist, blocksums, offsets, wl_small, wl_large, counts);
        scatter_kernel<<<260, 256, 0, stream>>>(tri, offsets, out);
        runsort_small_kernel<<<128, 256, 0, stream>>>(out, wl_small, counts);
        runsort_large_kernel<<<64, 256, 0, stream>>>(out, wl_large, counts);
    } else {
        float*    S         = (float*)(ws);
        float*    Msum      = (float*)(ws + 524288);
        uint32_t* hist      = (uint32_t*)(ws + 532480);
        uint32_t* counts    = (uint32_t*)(ws + 794624);
        uint32_t* offsets   = (uint32_t*)(ws + 794688);
        uint32_t* blocksums = (uint32_t*)(ws + 1056832);
        float*    tri       = (float*)(ws + 1057856);
        uint2*    wl_small  = (uint2*)(ws + 1324096);
        uint2*    wl_large  = (uint2*)(ws + 1590336);

        hipMemsetAsync(d_ws, 0, 794688, stream);
        cov_kernel_a<<<BATCHES * CHUNKS_PER_BATCH, 256, 0, stream>>>(x, S, Msum);
        finalize_kernel<<<(BATCHES * 4096) / 256, 256, 0, stream>>>(S, Msum, tri, hist);
        scanA_kernel<<<256, 256, 0, stream>>>(hist, blocksums);
        scanB_kernel<<<256, 256, 0, stream>>>(hist, blocksums, offsets, wl_small, wl_large, counts);
        scatter_kernel<<<260, 256, 0, stream>>>(tri, offsets, out);
        runsort_small_kernel<<<128, 256, 0, stream>>>(out, wl_small, counts);
        runsort_large_kernel<<<64, 256, 0, stream>>>(out, wl_large, counts);
    }
}

// Round 5
// 313.672 us; speedup vs baseline: 1.0619x; 1.0619x over previous
//
#include <hip/hip_runtime.h>
#include <stdint.h>

// CovPool: B=32, N=16384, D=64 fp32 -> per-batch cov (64x64), triu, globally
// sorted 66560 fp32 outputs.
// R5: (a) 18-bit bucket key (262144 buckets) -> runs ~16-25 instead of ~65-80,
// nearly all cleanup sorts take the barrier-free wave path; fused single
// runsort kernel; widened two-level scan. (b) cov launch_bounds (256,4)->(256,3)
// to stop VGPR spilling (body needs ~105 live regs, old cap was 128).
//
// Partial-path ws layout (zero region first = 1048640 B):
//   hist      [262144 u32]      @ 0
//   counts    [16 u32]          @ 1048576  <- zero region ends 1048640
//   offsets   [262144 u32]      @ 1048640
//   blocksums [1024 u32]        @ 2097216
//   tri       [66560 f32]       @ 2101312
//   wl_small  [33280 uint2]     @ 2367552
//   wl_large  [4096 uint2]      @ 2633792
//   partials  [1024][2624] f32  @ 2666560  (ends 13414464)

#define BATCHES 32
#define NSAMP   16384
#define DIM     64
#define LAMBDA  0.01f
#define NTRI    2080
#define NOUT    (BATCHES * NTRI)   // 66560

#define CHUNKS_PER_BATCH 32
#define SAMP_PER_BLOCK   (NSAMP / CHUNKS_PER_BATCH)  // 512
#define SAMP_PER_WAVE    (SAMP_PER_BLOCK / 4)        // 128
#define PARTIAL_STRIDE   2624                        // 2560 S + 64 msum

#define KEY_SHIFT 14                                 // top 18 bits
#define NBUCKET   (1 << 18)
#define SMALL_MAX 64u
#define SORT_CAP  8192

typedef __attribute__((ext_vector_type(4))) float f32x4;
typedef __attribute__((ext_vector_type(8))) short s16x8;

__device__ __forceinline__ uint32_t f32_to_bf16(float f) {
    uint32_t u = __builtin_bit_cast(uint32_t, f);
    return (u + 0x7FFFu + ((u >> 16) & 1u)) >> 16;   // RNE
}

__device__ __forceinline__ uint32_t sort_key(float v) {
    uint32_t u = __builtin_bit_cast(uint32_t, v);
    return u ^ (uint32_t)(((int32_t)u >> 31) | 0x80000000u);
}

__constant__ const int c_tmi[10] = {0, 0, 0, 0, 1, 1, 1, 2, 2, 3};
__constant__ const int c_tni[10] = {0, 1, 2, 3, 1, 2, 3, 2, 3, 3};

// ============ shared device body: direct-load MFMA K-loop + tree reduce ======
struct CovLds {
    float red[2][64][41];     // 20992 B (epilogue tree)
    float msum_red[4][64];    // 1024 B
};

template <typename EpilogueFn>
__device__ __forceinline__ void cov_body(const float* __restrict__ x, CovLds& L,
                                         EpilogueFn epi) {
    const int tid  = threadIdx.x;
    const int wave = tid >> 6;
    const int lane = tid & 63;
    const int b     = blockIdx.x / CHUNKS_PER_BATCH;
    const int chunk = blockIdx.x % CHUNKS_PER_BATCH;
    const int n_start = chunk * SAMP_PER_BLOCK + wave * SAMP_PER_WAVE;

    const int l15  = lane & 15;
    const int quad = lane >> 4;

    // lane (quad,l15) loads x[s0 + quad*8 + j][t*16 + l15] -> A/B fragment
    // layout (m/n = l15, k = quad*8+j) directly; offsets are immediates.
    const float* xw = x + ((size_t)b * NSAMP + n_start) * DIM
                        + quad * 8 * DIM + l15;

    f32x4 acc[10];
#pragma unroll
    for (int t = 0; t < 10; ++t) acc[t] = (f32x4){0.f, 0.f, 0.f, 0.f};
    float sum_t[4] = {0.f, 0.f, 0.f, 0.f};

    for (int kc = 0; kc < SAMP_PER_WAVE / 32; ++kc) {
        const float* xs = xw + kc * 32 * DIM;
        float v[8][4];
#pragma unroll
        for (int j = 0; j < 8; ++j)
#pragma unroll
            for (int t = 0; t < 4; ++t)
                v[j][t] = xs[j * DIM + t * 16];   // 32 independent dword loads

#pragma unroll
        for (int j = 0; j < 8; ++j)
#pragma unroll
            for (int t = 0; t < 4; ++t) sum_t[t] += v[j][t];

        s16x8 frag[4];
#pragma unroll
        for (int t = 0; t < 4; ++t) {
            uint32_t pk0 = f32_to_bf16(v[0][t]) | (f32_to_bf16(v[1][t]) << 16);
            uint32_t pk1 = f32_to_bf16(v[2][t]) | (f32_to_bf16(v[3][t]) << 16);
            uint32_t pk2 = f32_to_bf16(v[4][t]) | (f32_to_bf16(v[5][t]) << 16);
            uint32_t pk3 = f32_to_bf16(v[6][t]) | (f32_to_bf16(v[7][t]) << 16);
            frag[t] = __builtin_bit_cast(s16x8, make_uint4(pk0, pk1, pk2, pk3));
        }

        acc[0] = __builtin_amdgcn_mfma_f32_16x16x32_bf16(frag[0], frag[0], acc[0], 0, 0, 0);
        acc[1] = __builtin_amdgcn_mfma_f32_16x16x32_bf16(frag[0], frag[1], acc[1], 0, 0, 0);
        acc[2] = __builtin_amdgcn_mfma_f32_16x16x32_bf16(frag[0], frag[2], acc[2], 0, 0, 0);
        acc[3] = __builtin_amdgcn_mfma_f32_16x16x32_bf16(frag[0], frag[3], acc[3], 0, 0, 0);
        acc[4] = __builtin_amdgcn_mfma_f32_16x16x32_bf16(frag[1], frag[1], acc[4], 0, 0, 0);
        acc[5] = __builtin_amdgcn_mfma_f32_16x16x32_bf16(frag[1], frag[2], acc[5], 0, 0, 0);
        acc[6] = __builtin_amdgcn_mfma_f32_16x16x32_bf16(frag[1], frag[3], acc[6], 0, 0, 0);
        acc[7] = __builtin_amdgcn_mfma_f32_16x16x32_bf16(frag[2], frag[2], acc[7], 0, 0, 0);
        acc[8] = __builtin_amdgcn_mfma_f32_16x16x32_bf16(frag[2], frag[3], acc[8], 0, 0, 0);
        acc[9] = __builtin_amdgcn_mfma_f32_16x16x32_bf16(frag[3], frag[3], acc[9], 0, 0, 0);
    }

    // ---- per-dim mean partials: sum over the 4 quads ----
#pragma unroll
    for (int t = 0; t < 4; ++t) {
        sum_t[t] += __shfl_xor(sum_t[t], 16, 64);
        sum_t[t] += __shfl_xor(sum_t[t], 32, 64);
    }
    if (lane < 16) {
#pragma unroll
        for (int t = 0; t < 4; ++t) L.msum_red[wave][t * 16 + lane] = sum_t[t];
    }

    // ---- in-block tree reduction of 4 waves into wave0 ----
    __syncthreads();
    if (wave == 1 || wave == 3) {
        int slot = wave >> 1;
#pragma unroll
        for (int t = 0; t < 10; ++t)
#pragma unroll
            for (int r = 0; r < 4; ++r) L.red[slot][lane][t * 4 + r] = acc[t][r];
    }
    __syncthreads();
    if (wave == 0 || wave == 2) {
        int slot = wave >> 1;
#pragma unroll
        for (int t = 0; t < 10; ++t)
#pragma unroll
            for (int r = 0; r < 4; ++r) acc[t][r] += L.red[slot][lane][t * 4 + r];
    }
    __syncthreads();
    if (wave == 2) {
#pragma unroll
        for (int t = 0; t < 10; ++t)
#pragma unroll
            for (int r = 0; r < 4; ++r) L.red[0][lane][t * 4 + r] = acc[t][r];
    }
    __syncthreads();
    if (wave == 0) {
#pragma unroll
        for (int t = 0; t < 10; ++t)
#pragma unroll
            for (int r = 0; r < 4; ++r) acc[t][r] += L.red[0][lane][t * 4 + r];
        float msum_tot = L.msum_red[0][lane] + L.msum_red[1][lane] +
                         L.msum_red[2][lane] + L.msum_red[3][lane];
        epi(b, lane, quad, l15, acc, msum_tot);
    }
}

// ---------------- K1p: partial-store variant (no atomics) --------------------
__global__ __launch_bounds__(256, 3) void cov_kernel_p(const float* __restrict__ x,
                                                       float* __restrict__ partials) {
    __shared__ CovLds L;
    float* Pb = partials + (size_t)blockIdx.x * PARTIAL_STRIDE;
    cov_body(x, L, [&](int b, int lane, int quad, int l15, f32x4* acc, float msum) {
#pragma unroll
        for (int t = 0; t < 10; ++t)
#pragma unroll
            for (int r = 0; r < 4; ++r)
                Pb[t * 256 + r * 64 + lane] = acc[t][r];   // coalesced stores
        Pb[2560 + lane] = msum;
    });
}

// ---------------- K1a: atomic fallback variant -------------------------------
__global__ __launch_bounds__(256, 3) void cov_kernel_a(const float* __restrict__ x,
                                                       float* __restrict__ S,
                                                       float* __restrict__ Msum) {
    __shared__ CovLds L;
    cov_body(x, L, [&](int b, int lane, int quad, int l15, f32x4* acc, float msum) {
        float* Sb = S + b * DIM * DIM;
#pragma unroll
        for (int t = 0; t < 10; ++t) {
            int d0 = c_tmi[t] * 16 + quad * 4;
            int e  = c_tni[t] * 16 + l15;
#pragma unroll
            for (int r = 0; r < 4; ++r)
                atomicAdd(&Sb[(d0 + r) * DIM + e], acc[t][r]);
        }
        atomicAdd(&Msum[b * DIM + lane], msum);
    });
}

// ---------------- K2p: reduce partials + finalize + histogram ----------------
__global__ __launch_bounds__(256) void reduce_kernel(const float* __restrict__ partials,
                                                     float* __restrict__ tri,
                                                     uint32_t* __restrict__ hist) {
    __shared__ float msum[DIM];
    const int b = blockIdx.x, tid = threadIdx.x;
    const float* P0 = partials + (size_t)b * CHUNKS_PER_BATCH * PARTIAL_STRIDE;

    float acc10[10];
#pragma unroll
    for (int k = 0; k < 10; ++k) acc10[k] = 0.f;
    float ms = 0.f;
    for (int c = 0; c < CHUNKS_PER_BATCH; ++c) {
        const float* P = P0 + c * PARTIAL_STRIDE;
#pragma unroll
        for (int k = 0; k < 10; ++k) acc10[k] += P[tid + 256 * k];  // coalesced
        if (tid < DIM) ms += P[2560 + tid];
    }
    if (tid < DIM) msum[tid] = ms;
    __syncthreads();

    const int r = tid >> 6, lane = tid & 63, quad = lane >> 4, l15 = lane & 15;
#pragma unroll
    for (int k = 0; k < 10; ++k) {
        int row = c_tmi[k] * 16 + quad * 4 + r;
        int col = c_tni[k] * 16 + l15;
        if (row <= col) {
            float v = (acc10[k] - msum[row] * msum[col] * (1.0f / NSAMP)) * (1.0f / (NSAMP - 1));
            if (row == col) v += LAMBDA;
            int p = row * 64 - (row * (row + 1)) / 2 + col;
            tri[b * NTRI + p] = v;
            atomicAdd(&hist[sort_key(v) >> KEY_SHIFT], 1u);
        }
    }
}

// ---------------- K2a: finalize (atomic fallback path) -----------------------
__global__ void finalize_kernel(const float* __restrict__ S,
                                const float* __restrict__ Msum,
                                float* __restrict__ tri,
                                uint32_t* __restrict__ hist) {
    int t = blockIdx.x * blockDim.x + threadIdx.x;
    int b = t >> 12, de = t & 4095, d = de >> 6, e = de & 63;
    if (d > e) return;
    float ssum = S[b * 4096 + d * 64 + e];
    float md = Msum[b * 64 + d], me = Msum[b * 64 + e];
    float v = (ssum - md * me * (1.0f / NSAMP)) * (1.0f / (NSAMP - 1));
    if (d == e) v += LAMBDA;
    int p = d * 64 - (d * (d + 1)) / 2 + e;
    tri[b * NTRI + p] = v;
    atomicAdd(&hist[sort_key(v) >> KEY_SHIFT], 1u);
}

// ---------------- K3a: per-256-bucket partial sums (1024 blocks) -------------
__global__ __launch_bounds__(256) void scanA_kernel(const uint32_t* __restrict__ hist,
                                                    uint32_t* __restrict__ blocksums) {
    __shared__ uint32_t s[256];
    int tid = threadIdx.x;
    s[tid] = hist[blockIdx.x * 256 + tid];
    __syncthreads();
    for (int off = 128; off > 0; off >>= 1) {
        if (tid < off) s[tid] += s[tid + off];
        __syncthreads();
    }
    if (tid == 0) blocksums[blockIdx.x] = s[0];
}

// ---------------- K3b: offsets + worklists (1024 blocks) ---------------------
__global__ __launch_bounds__(256) void scanB_kernel(const uint32_t* __restrict__ hist,
                                                    const uint32_t* __restrict__ blocksums,
                                                    uint32_t* __restrict__ offsets,
                                                    uint2* __restrict__ wl_small,
                                                    uint2* __restrict__ wl_large,
                                                    uint32_t* __restrict__ counts) {
    __shared__ uint32_t bs[256];
    __shared__ uint32_t sc[256];
    __shared__ uint32_t base_sh;
    int tid = threadIdx.x, bid = blockIdx.x;

    // 1024 blocksums scanned as 256 x 4-serial
    uint32_t b4[4]; uint32_t s4 = 0;
#pragma unroll
    for (int i = 0; i < 4; ++i) { b4[i] = blocksums[4 * tid + i]; s4 += b4[i]; }
    bs[tid] = s4;
    __syncthreads();
    for (int off = 1; off < 256; off <<= 1) {
        uint32_t a = (tid >= off) ? bs[tid - off] : 0u;
        __syncthreads();
        bs[tid] += a;
        __syncthreads();
    }
    if (tid == (bid >> 2)) {
        uint32_t base = (tid > 0) ? bs[tid - 1] : 0u;
        for (int i = 0; i < (bid & 3); ++i) base += b4[i];
        base_sh = base;
    }

    // local scan of this block's 256 hist entries (barriers below also
    // publish base_sh)
    uint32_t v = hist[bid * 256 + tid];
    sc[tid] = v;
    __syncthreads();
    for (int off = 1; off < 256; off <<= 1) {
        uint32_t a = (tid >= off) ? sc[tid - off] : 0u;
        __syncthreads();
        sc[tid] += a;
        __syncthreads();
    }
    uint32_t excl = base_sh + sc[tid] - v;
    offsets[bid * 256 + tid] = excl;
    if (v >= 2u) {
        if (v <= SMALL_MAX) {
            uint32_t w = atomicAdd(&counts[0], 1u);
            wl_small[w] = make_uint2(excl, v);
        } else {
            uint32_t w = atomicAdd(&counts[1], 1u);
            wl_large[w] = make_uint2(excl, v);
        }
    }
}

// ---------------- K4: scatter into bucket positions --------------------------
__global__ void scatter_kernel(const float* __restrict__ tri,
                               uint32_t* __restrict__ offsets,
                               float* __restrict__ out) {
    int i = blockIdx.x * blockDim.x + threadIdx.x;
    if (i >= NOUT) return;
    float v = tri[i];
    uint32_t pos = atomicAdd(&offsets[sort_key(v) >> KEY_SHIFT], 1u);
    out[pos] = v;
}

// ---------------- K5: fused run cleanup (block-sort large, wave-sort small) --
__global__ __launch_bounds__(256) void runsort_kernel(float* __restrict__ out,
                                                      const uint2* __restrict__ wl_small,
                                                      const uint2* __restrict__ wl_large,
                                                      const uint32_t* __restrict__ counts) {
    __shared__ float buf[SORT_CAP];

    // phase 1: large runs (>64), whole-block LDS bitonic, block-stride
    uint32_t nl = counts[1];
    for (uint32_t w = blockIdx.x; w < nl; w += gridDim.x) {
        uint2 ent = wl_large[w];
        uint32_t start = ent.x, cnt = ent.y;
        if (cnt > SORT_CAP) continue;   // impossible for this distribution
        uint32_t m = 1;
        while (m < cnt) m <<= 1;
        for (uint32_t i = threadIdx.x; i < m; i += blockDim.x)
            buf[i] = (i < cnt) ? out[start + i] : __builtin_inff();
        __syncthreads();
        for (uint32_t k = 2; k <= m; k <<= 1) {
            for (uint32_t j = k >> 1; j > 0; j >>= 1) {
                for (uint32_t i = threadIdx.x; i < m; i += blockDim.x) {
                    uint32_t ixj = i ^ j;
                    if (ixj > i) {
                        float a = buf[i], c = buf[ixj];
                        bool up = ((i & k) == 0u);
                        if ((a > c) == up) { buf[i] = c; buf[ixj] = a; }
                    }
                }
                __syncthreads();
            }
        }
        for (uint32_t i = threadIdx.x; i < cnt; i += blockDim.x)
            out[start + i] = buf[i];
        __syncthreads();
    }

    // phase 2: small runs (2..64), barrier-free per-wave shuffle bitonic
    uint32_t ns = counts[0];
    int wave = threadIdx.x >> 6, lane = threadIdx.x & 63;
    for (uint32_t r = blockIdx.x * 4 + wave; r < ns; r += gridDim.x * 4) {
        uint2 e = wl_small[r];
        uint32_t start = e.x, cnt = e.y;
        float v = (lane < (int)cnt) ? out[start + lane] : __builtin_inff();
#pragma unroll
        for (uint32_t k = 2; k <= 64; k <<= 1)
            for (uint32_t j = k >> 1; j > 0; j >>= 1) {
                float p = __shfl_xor(v, (int)j, 64);
                bool keepmin = (((lane & k) == 0u) == ((lane & j) == 0u));
                v = keepmin ? fminf(v, p) : fmaxf(v, p);
            }
        if (lane < (int)cnt) out[start + lane] = v;
    }
}

// ---------------- shared tail launcher ---------------------------------------
static void launch_tail(uint32_t* hist, uint32_t* blocksums, uint32_t* offsets,
                        float* tri, uint2* wl_small, uint2* wl_large,
                        uint32_t* counts, float* out, hipStream_t stream) {
    scanA_kernel<<<NBUCKET / 256, 256, 0, stream>>>(hist, blocksums);
    scanB_kernel<<<NBUCKET / 256, 256, 0, stream>>>(hist, blocksums, offsets,
                                                    wl_small, wl_large, counts);
    scatter_kernel<<<(NOUT + 255) / 256, 256, 0, stream>>>(tri, offsets, out);
    runsort_kernel<<<1024, 256, 0, stream>>>(out, wl_small, wl_large, counts);
}

extern "C" void kernel_launch(void* const* d_in, const int* in_sizes, int n_in,
                              void* d_out, int out_size, void* d_ws, size_t ws_size,
                              hipStream_t stream) {
    const float* x = (const float*)d_in[0];
    float* out = (float*)d_out;
    char* ws = (char*)d_ws;

    const size_t NEED_P = 2666560 + (size_t)1024 * PARTIAL_STRIDE * 4;  // 13.4 MB

    if (ws_size >= NEED_P) {
        uint32_t* hist      = (uint32_t*)(ws);
        uint32_t* counts    = (uint32_t*)(ws + 1048576);
        uint32_t* offsets   = (uint32_t*)(ws + 1048640);
        uint32_t* blocksums = (uint32_t*)(ws + 2097216);
        float*    tri       = (float*)(ws + 2101312);
        uint2*    wl_small  = (uint2*)(ws + 2367552);
        uint2*    wl_large  = (uint2*)(ws + 2633792);
        float*    partials  = (float*)(ws + 2666560);

        hipMemsetAsync(d_ws, 0, 1048640, stream);  // hist + counts
        cov_kernel_p<<<BATCHES * CHUNKS_PER_BATCH, 256, 0, stream>>>(x, partials);
        reduce_kernel<<<BATCHES, 256, 0, stream>>>(partials, tri, hist);
        launch_tail(hist, blocksums, offsets, tri, wl_small, wl_large, counts, out, stream);
    } else {
        // atomic fallback (small ws): S/Msum + same new tail
        float*    S         = (float*)(ws);
        float*    Msum      = (float*)(ws + 524288);
        uint32_t* hist      = (uint32_t*)(ws + 532480);
        uint32_t* counts    = (uint32_t*)(ws + 1581056);
        uint32_t* offsets   = (uint32_t*)(ws + 1581120);
        uint32_t* blocksums = (uint32_t*)(ws + 2629696);
        float*    tri       = (float*)(ws + 2633792);
        uint2*    wl_small  = (uint2*)(ws + 2900032);
        uint2*    wl_large  = (uint2*)(ws + 3166272);

        hipMemsetAsync(d_ws, 0, 1581120, stream);  // S + Msum + hist + counts
        cov_kernel_a<<<BATCHES * CHUNKS_PER_BATCH, 256, 0, stream>>>(x, S, Msum);
        finalize_kernel<<<(BATCHES * 4096) / 256, 256, 0, stream>>>(S, Msum, tri, hist);
        launch_tail(hist, blocksums, offsets, tri, wl_small, wl_large, counts, out, stream);
    }
}

// Round 7
// 302.796 us; speedup vs baseline: 1.1001x; 1.0359x over previous
//
#include <hip/hip_runtime.h>
#include <hip/hip_bf16.h>
#include <stdint.h>

// CovPool: B=32, N=16384, D=64 fp32 -> per-batch cov (64x64), triu, globally
// sorted 66560 fp32 outputs.
// R7 (=R6 fixed): packed v_cvt_pk_bf16_f32 conversion (memcpy-punned),
// 2-buffer software-pipelined cov K-loop, hist zeroing folded into cov,
// reduce 320 blocks.
//
// Partial-path ws layout:
//   hist      [262144 u32]      @ 0
//   counts    [16 u32]          @ 1048576
//   offsets   [262144 u32]      @ 1048640
//   blocksums [1024 u32]        @ 2097216
//   tri       [66560 f32]       @ 2101312
//   wl_small  [33280 uint2]     @ 2367552
//   wl_large  [4096 uint2]      @ 2633792
//   partials  [1024][2624] f32  @ 2666560  (ends 13414464)

#define BATCHES 32
#define NSAMP   16384
#define DIM     64
#define LAMBDA  0.01f
#define NTRI    2080
#define NOUT    (BATCHES * NTRI)   // 66560

#define CHUNKS_PER_BATCH 32
#define SAMP_PER_BLOCK   (NSAMP / CHUNKS_PER_BATCH)  // 512
#define SAMP_PER_WAVE    (SAMP_PER_BLOCK / 4)        // 128
#define PARTIAL_STRIDE   2624                        // 2560 S + 64 msum

#define KEY_SHIFT 14                                 // top 18 bits
#define NBUCKET   (1 << 18)
#define SMALL_MAX 64u
#define SORT_CAP  8192

typedef __attribute__((ext_vector_type(4))) float f32x4;
typedef __attribute__((ext_vector_type(8))) short s16x8;

__device__ __forceinline__ uint32_t sort_key(float v) {
    uint32_t u = __builtin_bit_cast(uint32_t, v);
    return u ^ (uint32_t)(((int32_t)u >> 31) | 0x80000000u);
}

__device__ __forceinline__ uint32_t cvt_pk_bf16(float lo, float hi) {
    __hip_bfloat162 bb = __float22bfloat162_rn(make_float2(lo, hi));  // v_cvt_pk_bf16_f32
    uint32_t u;
    __builtin_memcpy(&u, &bb, 4);
    return u;
}

__constant__ const int c_tmi[10] = {0, 0, 0, 0, 1, 1, 1, 2, 2, 3};
__constant__ const int c_tni[10] = {0, 1, 2, 3, 1, 2, 3, 2, 3, 3};

// ============ shared device body: pipelined direct-load MFMA K-loop ==========
struct CovLds {
    float red[2][64][41];     // 20992 B (epilogue tree)
    float msum_red[4][64];    // 1024 B
};

template <typename EpilogueFn>
__device__ __forceinline__ void cov_body(const float* __restrict__ x, CovLds& L,
                                         EpilogueFn epi) {
    const int tid  = threadIdx.x;
    const int wave = tid >> 6;
    const int lane = tid & 63;
    const int b     = blockIdx.x / CHUNKS_PER_BATCH;
    const int chunk = blockIdx.x % CHUNKS_PER_BATCH;
    const int n_start = chunk * SAMP_PER_BLOCK + wave * SAMP_PER_WAVE;

    const int l15  = lane & 15;
    const int quad = lane >> 4;

    // lane (quad,l15) loads x[s0 + quad*8 + j][t*16 + l15] -> A/B fragment
    // layout (m/n = l15, k = quad*8+j) directly; offsets are immediates.
    const float* xw = x + ((size_t)b * NSAMP + n_start) * DIM
                        + quad * 8 * DIM + l15;

    f32x4 acc[10];
#pragma unroll
    for (int t = 0; t < 10; ++t) acc[t] = (f32x4){0.f, 0.f, 0.f, 0.f};
    float sum_t[4] = {0.f, 0.f, 0.f, 0.f};

    float va[8][4], vb[8][4];

    auto loadit = [&](float (&v)[8][4], int kc) {
        const float* xs = xw + kc * 32 * DIM;
#pragma unroll
        for (int j = 0; j < 8; ++j)
#pragma unroll
            for (int t = 0; t < 4; ++t)
                v[j][t] = xs[j * DIM + t * 16];   // 32 independent dword loads
    };

    auto compute = [&](float (&v)[8][4]) {
#pragma unroll
        for (int j = 0; j < 8; ++j)
#pragma unroll
            for (int t = 0; t < 4; ++t) sum_t[t] += v[j][t];

        s16x8 frag[4];
#pragma unroll
        for (int t = 0; t < 4; ++t) {
            uint32_t pk0 = cvt_pk_bf16(v[0][t], v[1][t]);
            uint32_t pk1 = cvt_pk_bf16(v[2][t], v[3][t]);
            uint32_t pk2 = cvt_pk_bf16(v[4][t], v[5][t]);
            uint32_t pk3 = cvt_pk_bf16(v[6][t], v[7][t]);
            frag[t] = __builtin_bit_cast(s16x8, make_uint4(pk0, pk1, pk2, pk3));
        }

        acc[0] = __builtin_amdgcn_mfma_f32_16x16x32_bf16(frag[0], frag[0], acc[0], 0, 0, 0);
        acc[1] = __builtin_amdgcn_mfma_f32_16x16x32_bf16(frag[0], frag[1], acc[1], 0, 0, 0);
        acc[2] = __builtin_amdgcn_mfma_f32_16x16x32_bf16(frag[0], frag[2], acc[2], 0, 0, 0);
        acc[3] = __builtin_amdgcn_mfma_f32_16x16x32_bf16(frag[0], frag[3], acc[3], 0, 0, 0);
        acc[4] = __builtin_amdgcn_mfma_f32_16x16x32_bf16(frag[1], frag[1], acc[4], 0, 0, 0);
        acc[5] = __builtin_amdgcn_mfma_f32_16x16x32_bf16(frag[1], frag[2], acc[5], 0, 0, 0);
        acc[6] = __builtin_amdgcn_mfma_f32_16x16x32_bf16(frag[1], frag[3], acc[6], 0, 0, 0);
        acc[7] = __builtin_amdgcn_mfma_f32_16x16x32_bf16(frag[2], frag[2], acc[7], 0, 0, 0);
        acc[8] = __builtin_amdgcn_mfma_f32_16x16x32_bf16(frag[2], frag[3], acc[8], 0, 0, 0);
        acc[9] = __builtin_amdgcn_mfma_f32_16x16x32_bf16(frag[3], frag[3], acc[9], 0, 0, 0);
    };

    // hand-unrolled 2-buffer pipeline over SAMP_PER_WAVE/32 = 4 iterations:
    // loads of the next chunk are always in flight behind compute.
    loadit(va, 0);
    loadit(vb, 1);
    compute(va);        // waits only on va's 32 loads
    loadit(va, 2);
    compute(vb);
    loadit(vb, 3);
    compute(va);
    compute(vb);

    // ---- per-dim mean partials: sum over the 4 quads ----
#pragma unroll
    for (int t = 0; t < 4; ++t) {
        sum_t[t] += __shfl_xor(sum_t[t], 16, 64);
        sum_t[t] += __shfl_xor(sum_t[t], 32, 64);
    }
    if (lane < 16) {
#pragma unroll
        for (int t = 0; t < 4; ++t) L.msum_red[wave][t * 16 + lane] = sum_t[t];
    }

    // ---- in-block tree reduction of 4 waves into wave0 ----
    __syncthreads();
    if (wave == 1 || wave == 3) {
        int slot = wave >> 1;
#pragma unroll
        for (int t = 0; t < 10; ++t)
#pragma unroll
            for (int r = 0; r < 4; ++r) L.red[slot][lane][t * 4 + r] = acc[t][r];
    }
    __syncthreads();
    if (wave == 0 || wave == 2) {
        int slot = wave >> 1;
#pragma unroll
        for (int t = 0; t < 10; ++t)
#pragma unroll
            for (int r = 0; r < 4; ++r) acc[t][r] += L.red[slot][lane][t * 4 + r];
    }
    __syncthreads();
    if (wave == 2) {
#pragma unroll
        for (int t = 0; t < 10; ++t)
#pragma unroll
            for (int r = 0; r < 4; ++r) L.red[0][lane][t * 4 + r] = acc[t][r];
    }
    __syncthreads();
    if (wave == 0) {
#pragma unroll
        for (int t = 0; t < 10; ++t)
#pragma unroll
            for (int r = 0; r < 4; ++r) acc[t][r] += L.red[0][lane][t * 4 + r];
        float msum_tot = L.msum_red[0][lane] + L.msum_red[1][lane] +
                         L.msum_red[2][lane] + L.msum_red[3][lane];
        epi(b, lane, quad, l15, acc, msum_tot);
    }
}

// ---------------- K1p: partial-store variant + hist zeroing ------------------
__global__ __launch_bounds__(256, 3) void cov_kernel_p(const float* __restrict__ x,
                                                       float* __restrict__ partials,
                                                       uint32_t* __restrict__ hist,
                                                       uint32_t* __restrict__ counts) {
    // fold the hist/counts zeroing in: grid 1024 x 256 == 262144 == NBUCKET
    hist[blockIdx.x * 256 + threadIdx.x] = 0u;
    if (blockIdx.x == 0 && threadIdx.x < 16) counts[threadIdx.x] = 0u;

    __shared__ CovLds L;
    float* Pb = partials + (size_t)blockIdx.x * PARTIAL_STRIDE;
    cov_body(x, L, [&](int b, int lane, int quad, int l15, f32x4* acc, float msum) {
#pragma unroll
        for (int t = 0; t < 10; ++t)
#pragma unroll
            for (int r = 0; r < 4; ++r)
                Pb[t * 256 + r * 64 + lane] = acc[t][r];   // coalesced stores
        Pb[2560 + lane] = msum;
    });
}

// ---------------- K1a: atomic fallback variant -------------------------------
__global__ __launch_bounds__(256, 3) void cov_kernel_a(const float* __restrict__ x,
                                                       float* __restrict__ S,
                                                       float* __restrict__ Msum) {
    __shared__ CovLds L;
    cov_body(x, L, [&](int b, int lane, int quad, int l15, f32x4* acc, float msum) {
        float* Sb = S + b * DIM * DIM;
#pragma unroll
        for (int t = 0; t < 10; ++t) {
            int d0 = c_tmi[t] * 16 + quad * 4;
            int e  = c_tni[t] * 16 + l15;
#pragma unroll
            for (int r = 0; r < 4; ++r)
                atomicAdd(&Sb[(d0 + r) * DIM + e], acc[t][r]);
        }
        atomicAdd(&Msum[b * DIM + lane], msum);
    });
}

// ---------------- K2p: reduce partials + finalize + histogram (320 blocks) ---
__global__ __launch_bounds__(256) void reduce_kernel(const float* __restrict__ partials,
                                                     float* __restrict__ tri,
                                                     uint32_t* __restrict__ hist) {
    const int b = blockIdx.x / 10, k = blockIdx.x % 10;
    const int tid = threadIdx.x;
    __shared__ float msum[DIM];
    const float* P0 = partials + (size_t)b * CHUNKS_PER_BATCH * PARTIAL_STRIDE;

    if (tid < DIM) {
        float ms = 0.f;
#pragma unroll
        for (int c = 0; c < CHUNKS_PER_BATCH; ++c)
            ms += P0[c * PARTIAL_STRIDE + 2560 + tid];
        msum[tid] = ms;
    }

    float a = 0.f;
#pragma unroll
    for (int c = 0; c < CHUNKS_PER_BATCH; ++c)
        a += P0[c * PARTIAL_STRIDE + k * 256 + tid];   // coalesced
    __syncthreads();

    const int r = tid >> 6, lane = tid & 63, quad = lane >> 4, l15 = lane & 15;
    const int row = c_tmi[k] * 16 + quad * 4 + r;
    const int col = c_tni[k] * 16 + l15;
    if (row <= col) {
        float v = (a - msum[row] * msum[col] * (1.0f / NSAMP)) * (1.0f / (NSAMP - 1));
        if (row == col) v += LAMBDA;
        int p = row * 64 - (row * (row + 1)) / 2 + col;
        tri[b * NTRI + p] = v;
        atomicAdd(&hist[sort_key(v) >> KEY_SHIFT], 1u);
    }
}

// ---------------- K2a: finalize (atomic fallback path) -----------------------
__global__ void finalize_kernel(const float* __restrict__ S,
                                const float* __restrict__ Msum,
                                float* __restrict__ tri,
                                uint32_t* __restrict__ hist) {
    int t = blockIdx.x * blockDim.x + threadIdx.x;
    int b = t >> 12, de = t & 4095, d = de >> 6, e = de & 63;
    if (d > e) return;
    float ssum = S[b * 4096 + d * 64 + e];
    float md = Msum[b * 64 + d], me = Msum[b * 64 + e];
    float v = (ssum - md * me * (1.0f / NSAMP)) * (1.0f / (NSAMP - 1));
    if (d == e) v += LAMBDA;
    int p = d * 64 - (d * (d + 1)) / 2 + e;
    tri[b * NTRI + p] = v;
    atomicAdd(&hist[sort_key(v) >> KEY_SHIFT], 1u);
}

// ---------------- K3a: per-256-bucket partial sums (1024 blocks) -------------
__global__ __launch_bounds__(256) void scanA_kernel(const uint32_t* __restrict__ hist,
                                                    uint32_t* __restrict__ blocksums) {
    __shared__ uint32_t s[256];
    int tid = threadIdx.x;
    s[tid] = hist[blockIdx.x * 256 + tid];
    __syncthreads();
    for (int off = 128; off > 0; off >>= 1) {
        if (tid < off) s[tid] += s[tid + off];
        __syncthreads();
    }
    if (tid == 0) blocksums[blockIdx.x] = s[0];
}

// ---------------- K3b: offsets + worklists (1024 blocks) ---------------------
__global__ __launch_bounds__(256) void scanB_kernel(const uint32_t* __restrict__ hist,
                                                    const uint32_t* __restrict__ blocksums,
                                                    uint32_t* __restrict__ offsets,
                                                    uint2* __restrict__ wl_small,
                                                    uint2* __restrict__ wl_large,
                                                    uint32_t* __restrict__ counts) {
    __shared__ uint32_t bs[256];
    __shared__ uint32_t sc[256];
    __shared__ uint32_t base_sh;
    int tid = threadIdx.x, bid = blockIdx.x;

    uint32_t b4[4]; uint32_t s4 = 0;
#pragma unroll
    for (int i = 0; i < 4; ++i) { b4[i] = blocksums[4 * tid + i]; s4 += b4[i]; }
    bs[tid] = s4;
    __syncthreads();
    for (int off = 1; off < 256; off <<= 1) {
        uint32_t a = (tid >= off) ? bs[tid - off] : 0u;
        __syncthreads();
        bs[tid] += a;
        __syncthreads();
    }
    if (tid == (bid >> 2)) {
        uint32_t base = (tid > 0) ? bs[tid - 1] : 0u;
        for (int i = 0; i < (bid & 3); ++i) base += b4[i];
        base_sh = base;
    }

    uint32_t v = hist[bid * 256 + tid];
    sc[tid] = v;
    __syncthreads();
    for (int off = 1; off < 256; off <<= 1) {
        uint32_t a = (tid >= off) ? sc[tid - off] : 0u;
        __syncthreads();
        sc[tid] += a;
        __syncthreads();
    }
    uint32_t excl = base_sh + sc[tid] - v;
    offsets[bid * 256 + tid] = excl;
    if (v >= 2u) {
        if (v <= SMALL_MAX) {
            uint32_t w = atomicAdd(&counts[0], 1u);
            wl_small[w] = make_uint2(excl, v);
        } else {
            uint32_t w = atomicAdd(&counts[1], 1u);
            wl_large[w] = make_uint2(excl, v);
        }
    }
}

// ---------------- K4: scatter into bucket positions --------------------------
__global__ void scatter_kernel(const float* __restrict__ tri,
                               uint32_t* __restrict__ offsets,
                               float* __restrict__ out) {
    int i = blockIdx.x * blockDim.x + threadIdx.x;
    if (i >= NOUT) return;
    float v = tri[i];
    uint32_t pos = atomicAdd(&offsets[sort_key(v) >> KEY_SHIFT], 1u);
    out[pos] = v;
}

// ---------------- K5: fused run cleanup (block-sort large, wave-sort small) --
__global__ __launch_bounds__(256) void runsort_kernel(float* __restrict__ out,
                                                      const uint2* __restrict__ wl_small,
                                                      const uint2* __restrict__ wl_large,
                                                      const uint32_t* __restrict__ counts) {
    __shared__ float buf[SORT_CAP];

    uint32_t nl = counts[1];
    for (uint32_t w = blockIdx.x; w < nl; w += gridDim.x) {
        uint2 ent = wl_large[w];
        uint32_t start = ent.x, cnt = ent.y;
        if (cnt > SORT_CAP) continue;
        uint32_t m = 1;
        while (m < cnt) m <<= 1;
        for (uint32_t i = threadIdx.x; i < m; i += blockDim.x)
            buf[i] = (i < cnt) ? out[start + i] : __builtin_inff();
        __syncthreads();
        for (uint32_t k = 2; k <= m; k <<= 1) {
            for (uint32_t j = k >> 1; j > 0; j >>= 1) {
                for (uint32_t i = threadIdx.x; i < m; i += blockDim.x) {
                    uint32_t ixj = i ^ j;
                    if (ixj > i) {
                        float a = buf[i], c = buf[ixj];
                        bool up = ((i & k) == 0u);
                        if ((a > c) == up) { buf[i] = c; buf[ixj] = a; }
                    }
                }
                __syncthreads();
            }
        }
        for (uint32_t i = threadIdx.x; i < cnt; i += blockDim.x)
            out[start + i] = buf[i];
        __syncthreads();
    }

    uint32_t ns = counts[0];
    int wave = threadIdx.x >> 6, lane = threadIdx.x & 63;
    for (uint32_t r = blockIdx.x * 4 + wave; r < ns; r += gridDim.x * 4) {
        uint2 e = wl_small[r];
        uint32_t start = e.x, cnt = e.y;
        float v = (lane < (int)cnt) ? out[start + lane] : __builtin_inff();
#pragma unroll
        for (uint32_t k = 2; k <= 64; k <<= 1)
            for (uint32_t j = k >> 1; j > 0; j >>= 1) {
                float p = __shfl_xor(v, (int)j, 64);
                bool keepmin = (((lane & k) == 0u) == ((lane & j) == 0u));
                v = keepmin ? fminf(v, p) : fmaxf(v, p);
            }
        if (lane < (int)cnt) out[start + lane] = v;
    }
}

// ---------------- shared tail launcher ---------------------------------------
static void launch_tail(uint32_t* hist, uint32_t* blocksums, uint32_t* offsets,
                        float* tri, uint2* wl_small, uint2* wl_large,
                        uint32_t* counts, float* out, hipStream_t stream) {
    scanA_kernel<<<NBUCKET / 256, 256, 0, stream>>>(hist, blocksums);
    scanB_kernel<<<NBUCKET / 256, 256, 0, stream>>>(hist, blocksums, offsets,
                                                    wl_small, wl_large, counts);
    scatter_kernel<<<(NOUT + 255) / 256, 256, 0, stream>>>(tri, offsets, out);
    runsort_kernel<<<1024, 256, 0, stream>>>(out, wl_small, wl_large, counts);
}

extern "C" void kernel_launch(void* const* d_in, const int* in_sizes, int n_in,
                              void* d_out, int out_size, void* d_ws, size_t ws_size,
                              hipStream_t stream) {
    const float* x = (const float*)d_in[0];
    float* out = (float*)d_out;
    char* ws = (char*)d_ws;

    const size_t NEED_P = 2666560 + (size_t)1024 * PARTIAL_STRIDE * 4;  // 13.4 MB

    if (ws_size >= NEED_P) {
        uint32_t* hist      = (uint32_t*)(ws);
        uint32_t* counts    = (uint32_t*)(ws + 1048576);
        uint32_t* offsets   = (uint32_t*)(ws + 1048640);
        uint32_t* blocksums = (uint32_t*)(ws + 2097216);
        float*    tri       = (float*)(ws + 2101312);
        uint2*    wl_small  = (uint2*)(ws + 2367552);
        uint2*    wl_large  = (uint2*)(ws + 2633792);
        float*    partials  = (float*)(ws + 2666560);

        // no memset: cov zeroes hist+counts itself
        cov_kernel_p<<<BATCHES * CHUNKS_PER_BATCH, 256, 0, stream>>>(x, partials, hist, counts);
        reduce_kernel<<<BATCHES * 10, 256, 0, stream>>>(partials, tri, hist);
        launch_tail(hist, blocksums, offsets, tri, wl_small, wl_large, counts, out, stream);
    } else {
        float*    S         = (float*)(ws);
        float*    Msum      = (float*)(ws + 524288);
        uint32_t* hist      = (uint32_t*)(ws + 532480);
        uint32_t* counts    = (uint32_t*)(ws + 1581056);
        uint32_t* offsets   = (uint32_t*)(ws + 1581120);
        uint32_t* blocksums = (uint32_t*)(ws + 2629696);
        float*    tri       = (float*)(ws + 2633792);
        uint2*    wl_small  = (uint2*)(ws + 2900032);
        uint2*    wl_large  = (uint2*)(ws + 3166272);

        (void)hipMemsetAsync(d_ws, 0, 1581120, stream);
        cov_kernel_a<<<BATCHES * CHUNKS_PER_BATCH, 256, 0, stream>>>(x, S, Msum);
        finalize_kernel<<<(BATCHES * 4096) / 256, 256, 0, stream>>>(S, Msum, tri, hist);
        launch_tail(hist, blocksums, offsets, tri, wl_small, wl_large, counts, out, stream);
    }
}